// Round 1
// baseline (15531.879 us; speedup 1.0000x reference)
//
#include <hip/hip_runtime.h>
#include <math.h>

// ---------------------------------------------------------------------------
// BiLSTM-CRF tagger on MI355X.
//   T=2048, D=512, H=512, HD=256, L=2, NTAGS=20, START=18, END=19
// Pipeline (all on `stream`):
//   1. embed gather            x0[T][512]
//   2. xg GEMM layer0 (f+b)    xg = x0 @ Wih^T + bih     [T][1024] per dir
//   3. recurrence layer0       x1[T][512]  (f cols 0..255, b cols 256..511)
//   4. xg GEMM layer1 (f+b)
//   5. recurrence layer1       x2[T][512]
//   6. projection              feats[T][20]
//   7. viterbi (fwd + backtrace) -> d_out[0]=score, d_out[1..2048]=path
// ---------------------------------------------------------------------------

#define T_LEN 2048
#define DMODEL 512
#define HD 256
#define NTAGS 20
#define START_TAG 18
#define END_TAG 19

__device__ __forceinline__ float fsig(float x) {
  return 1.0f / (1.0f + __expf(-x));
}
__device__ __forceinline__ float ftanh(float x) {
  float xc = fminf(15.0f, fmaxf(-15.0f, x));
  float e = __expf(2.0f * xc);
  return (e - 1.0f) / (e + 1.0f);
}

// ---------------------------------------------------------------------------
// 1. Embedding gather: x0[t][:] = emb[sentence[t]][:]
// grid: T_LEN blocks, 128 threads; float4 per thread
// ---------------------------------------------------------------------------
__global__ void embed_k(const int* __restrict__ sent,
                        const float* __restrict__ emb,
                        float* __restrict__ x0) {
  int t = blockIdx.x;
  int tid = threadIdx.x;  // 0..127
  int tok = sent[t];
  const float4* src = (const float4*)(emb + (size_t)tok * DMODEL);
  float4* dst = (float4*)(x0 + (size_t)t * DMODEL);
  dst[tid] = src[tid];
}

// ---------------------------------------------------------------------------
// 2. xg GEMM: out[t][n] = sum_k X[t][k] * W[n][k] + b[n]
//    X: [2048][512], W: [1024][512], out: [2048][1024]
// 128x128 block tile, 8x8 per thread, k-tile 16.
// grid: (N/128=8, M/128=16, 2 dirs), block 256
// ---------------------------------------------------------------------------
__global__ __launch_bounds__(256) void gemm_xg_k(
    const float* __restrict__ X,
    const float* __restrict__ Wf, const float* __restrict__ Wb,
    const float* __restrict__ bf, const float* __restrict__ bb,
    float* __restrict__ outf, float* __restrict__ outb) {
  int bx = blockIdx.x;   // N tile (0..7)
  int by = blockIdx.y;   // M tile (0..15)
  int dir = blockIdx.z;
  const float* W = dir ? Wb : Wf;
  const float* bias = dir ? bb : bf;
  float* out = dir ? outb : outf;

  __shared__ __align__(16) float Xs[16][132];
  __shared__ __align__(16) float Ws[16][132];

  int tid = threadIdx.x;
  int tx = tid & 15;   // 0..15 -> N
  int ty = tid >> 4;   // 0..15 -> M

  float acc[8][8];
#pragma unroll
  for (int i = 0; i < 8; i++)
#pragma unroll
    for (int j = 0; j < 8; j++) acc[i][j] = 0.0f;

  for (int kt = 0; kt < DMODEL / 16; kt++) {
    __syncthreads();
#pragma unroll
    for (int l = 0; l < 2; l++) {
      int fi = tid + l * 256;        // 0..511  (128 rows x 4 float4)
      int row = fi >> 2;
      int kq = fi & 3;
      float4 xv = *(const float4*)(X + (size_t)(by * 128 + row) * DMODEL + kt * 16 + kq * 4);
      Xs[kq * 4 + 0][row] = xv.x;
      Xs[kq * 4 + 1][row] = xv.y;
      Xs[kq * 4 + 2][row] = xv.z;
      Xs[kq * 4 + 3][row] = xv.w;
      float4 wv = *(const float4*)(W + (size_t)(bx * 128 + row) * DMODEL + kt * 16 + kq * 4);
      Ws[kq * 4 + 0][row] = wv.x;
      Ws[kq * 4 + 1][row] = wv.y;
      Ws[kq * 4 + 2][row] = wv.z;
      Ws[kq * 4 + 3][row] = wv.w;
    }
    __syncthreads();
#pragma unroll
    for (int k = 0; k < 16; k++) {
      float4 a0 = *(const float4*)&Xs[k][ty * 4];
      float4 a1 = *(const float4*)&Xs[k][64 + ty * 4];
      float4 b0 = *(const float4*)&Ws[k][tx * 4];
      float4 b1 = *(const float4*)&Ws[k][64 + tx * 4];
      float a[8] = {a0.x, a0.y, a0.z, a0.w, a1.x, a1.y, a1.z, a1.w};
      float b[8] = {b0.x, b0.y, b0.z, b0.w, b1.x, b1.y, b1.z, b1.w};
#pragma unroll
      for (int i = 0; i < 8; i++)
#pragma unroll
        for (int j = 0; j < 8; j++) acc[i][j] += a[i] * b[j];
    }
  }

  float4 bv0 = *(const float4*)(bias + bx * 128 + tx * 4);
  float4 bv1 = *(const float4*)(bias + bx * 128 + 64 + tx * 4);
  float bb8[8] = {bv0.x, bv0.y, bv0.z, bv0.w, bv1.x, bv1.y, bv1.z, bv1.w};
#pragma unroll
  for (int i = 0; i < 8; i++) {
    int row = by * 128 + ((i < 4) ? (ty * 4 + i) : (64 + ty * 4 + (i - 4)));
    float4 o0 = {acc[i][0] + bb8[0], acc[i][1] + bb8[1], acc[i][2] + bb8[2], acc[i][3] + bb8[3]};
    float4 o1 = {acc[i][4] + bb8[4], acc[i][5] + bb8[5], acc[i][6] + bb8[6], acc[i][7] + bb8[7]};
    *(float4*)(out + (size_t)row * 1024 + bx * 128 + tx * 4) = o0;
    *(float4*)(out + (size_t)row * 1024 + bx * 128 + 64 + tx * 4) = o1;
  }
}

// ---------------------------------------------------------------------------
// 3/5. Recurrence. grid: (8 chunks, 2 dirs), block 256.
// WG (kc,dir) owns gate rows {g*256 + kc*32 + kl : g in 0..3, kl in 0..31}.
// Weights in VGPRs (32 float4 per thread). Per step:
//   z = Whh-slab . h  (h broadcast from LDS) -> pair-reduce -> + xg + bhh
//   gate threads (tid<32) update c, write h chunk to x_next[t]
//   threadfence + release atomicAdd on flags[dir]; all threads acquire-spin
//   reload full h (256 f) from x_next[t] into LDS
// ---------------------------------------------------------------------------
__global__ __launch_bounds__(256) void recur_k(
    const float* __restrict__ xg_f, const float* __restrict__ xg_b,
    const float* __restrict__ Whh_f, const float* __restrict__ Whh_b,
    const float* __restrict__ bhh_f, const float* __restrict__ bhh_b,
    float* __restrict__ xnext, unsigned int* __restrict__ flags) {
  int kc = blockIdx.x;          // 0..7
  int dir = blockIdx.y;         // 0=f, 1=b
  int tid = threadIdx.x;        // 0..255

  const float* Whh = dir ? Whh_b : Whh_f;
  const float* bhh = dir ? bhh_b : bhh_f;
  const float* xg = dir ? xg_b : xg_f;
  unsigned int* flag = flags + dir;

  int r = tid >> 1;             // local row 0..127
  int half = tid & 1;           // which 128-col half
  int g = r >> 5;               // gate 0..3 (i,f,g,o)
  int kl = r & 31;
  int grow = g * 256 + kc * 32 + kl;  // global gate row 0..1023

  // load weight slab into registers
  float4 Wv[32];
  const float4* wrow = (const float4*)(Whh + (size_t)grow * HD + half * 128);
#pragma unroll
  for (int j = 0; j < 32; j++) Wv[j] = wrow[j];
  float bias = bhh[grow];

  __shared__ __align__(16) float hbuf[HD];   // h_{t-1}
  __shared__ float zbuf[128];
  hbuf[tid & 255] = 0.0f;
  if (tid < HD - 256 + 256) {}  // (all 256 threads covered above)
  __syncthreads();

  float c = 0.0f;  // cell state, used by tid<32

#pragma unroll 1
  for (int it = 0; it < T_LEN; ++it) {
    int t = dir ? (T_LEN - 1 - it) : it;

    // prefetch xg early (even lanes only; consumed after the FMA loop)
    float xgv = 0.0f;
    if (!half) xgv = xg[(size_t)t * 1024 + grow];

    const float4* h4 = (const float4*)hbuf + half * 32;
    float4 acc = {0.f, 0.f, 0.f, 0.f};
#pragma unroll
    for (int j = 0; j < 32; j++) {
      float4 hv = h4[j];
      acc.x += Wv[j].x * hv.x;
      acc.y += Wv[j].y * hv.y;
      acc.z += Wv[j].z * hv.z;
      acc.w += Wv[j].w * hv.w;
    }
    float s = (acc.x + acc.y) + (acc.z + acc.w);
    s += __shfl_xor(s, 1, 64);   // combine the two halves of the row
    if (!half) zbuf[r] = s + xgv + bias;
    __syncthreads();

    if (tid < 32) {
      float zi = zbuf[tid];
      float zf = zbuf[32 + tid];
      float zg = zbuf[64 + tid];
      float zo = zbuf[96 + tid];
      c = fsig(zf) * c + fsig(zi) * ftanh(zg);
      float h = fsig(zo) * ftanh(c);
      xnext[(size_t)t * DMODEL + dir * HD + kc * 32 + tid] = h;
    }
    __syncthreads();  // gate stores complete (vmcnt drained) before arrival

    if (tid == 0) {
      __threadfence();
      __hip_atomic_fetch_add(flag, 1u, __ATOMIC_RELEASE, __HIP_MEMORY_SCOPE_AGENT);
    }
    unsigned int target = 8u * (unsigned)(it + 1);
    while (__hip_atomic_load(flag, __ATOMIC_ACQUIRE, __HIP_MEMORY_SCOPE_AGENT) < target) {
    }

    // reload full h_t into LDS for next step
    if (tid < 64) {
      ((float4*)hbuf)[tid] = ((const float4*)(xnext + (size_t)t * DMODEL + dir * HD))[tid];
    }
    __syncthreads();
  }
}

// ---------------------------------------------------------------------------
// 6. Projection: feats[t][n] = x2[t][:] . W_out[n][:] + b_out[n]
// grid: T_LEN blocks, 256 threads (8 segs x 32 lanes, 20 active tags)
// ---------------------------------------------------------------------------
__global__ void proj_k(const float* __restrict__ x2,
                       const float* __restrict__ Wo,
                       const float* __restrict__ bo,
                       float* __restrict__ feats) {
  int t = blockIdx.x;
  int tid = threadIdx.x;
  int n = tid & 31;
  int seg = tid >> 5;   // 0..7
  __shared__ float red[8][32];
  float s = 0.0f;
  if (n < NTAGS) {
    const float* xr = x2 + (size_t)t * DMODEL + seg * 64;
    const float* wr = Wo + (size_t)n * DMODEL + seg * 64;
#pragma unroll
    for (int j = 0; j < 64; j++) s += xr[j] * wr[j];
  }
  red[seg][n] = s;
  __syncthreads();
  if (tid < NTAGS) {
    float tot = bo[tid];
#pragma unroll
    for (int k = 0; k < 8; k++) tot += red[k][tid];
    feats[(size_t)t * NTAGS + tid] = tot;
  }
}

// ---------------------------------------------------------------------------
// 7. Viterbi: single block, 64 threads (one wave). v in LDS, tr row in regs,
// backpointers in LDS (40KB). Lane 0 does the backtrace.
// out[0] = score, out[1+t] = path[t] (as float)
// ---------------------------------------------------------------------------
__global__ void viterbi_k(const float* __restrict__ feats,
                          const float* __restrict__ tr,
                          float* __restrict__ out) {
  __shared__ float v[NTAGS];
  __shared__ unsigned char bp[T_LEN * NTAGS];  // 40KB
  __shared__ float term[NTAGS];
  int tid = threadIdx.x;

  float trrow[NTAGS];
  if (tid < NTAGS) {
#pragma unroll
    for (int p = 0; p < NTAGS; p++) trrow[p] = tr[tid * NTAGS + p];
    v[tid] = (tid == START_TAG) ? 0.0f : -10000.0f;
  }
  __syncthreads();

#pragma unroll 1
  for (int t = 0; t < T_LEN; t++) {
    float fv = 0.0f;
    if (tid < NTAGS) fv = feats[(size_t)t * NTAGS + tid];
    float best = -3.4e38f;
    int arg = 0;
    if (tid < NTAGS) {
#pragma unroll
      for (int p = 0; p < NTAGS; p++) {
        float sc = v[p] + trrow[p];
        if (sc > best) { best = sc; arg = p; }
      }
      bp[t * NTAGS + tid] = (unsigned char)arg;
    }
    __syncthreads();
    if (tid < NTAGS) v[tid] = best + fv;
    __syncthreads();
  }

  if (tid < NTAGS) term[tid] = v[tid] + tr[END_TAG * NTAGS + tid];
  __syncthreads();
  if (tid == 0) {
    float bs = term[0];
    int bi = 0;
    for (int p = 1; p < NTAGS; p++) {
      if (term[p] > bs) { bs = term[p]; bi = p; }
    }
    out[0] = bs;
    int tag = bi;
    for (int t = T_LEN - 1; t >= 0; t--) {
      out[1 + t] = (float)tag;
      tag = bp[t * NTAGS + tag];
    }
  }
}

// ---------------------------------------------------------------------------
// Launch
// ---------------------------------------------------------------------------
extern "C" void kernel_launch(void* const* d_in, const int* in_sizes, int n_in,
                              void* d_out, int out_size, void* d_ws, size_t ws_size,
                              hipStream_t stream) {
  const int* sent = (const int*)d_in[0];
  const float* emb = (const float*)d_in[1];
  // per layer/dir: Wih, Whh, bih, bhh
  const float* l0f_Wih = (const float*)d_in[2];
  const float* l0f_Whh = (const float*)d_in[3];
  const float* l0f_bih = (const float*)d_in[4];
  const float* l0f_bhh = (const float*)d_in[5];
  const float* l0b_Wih = (const float*)d_in[6];
  const float* l0b_Whh = (const float*)d_in[7];
  const float* l0b_bih = (const float*)d_in[8];
  const float* l0b_bhh = (const float*)d_in[9];
  const float* l1f_Wih = (const float*)d_in[10];
  const float* l1f_Whh = (const float*)d_in[11];
  const float* l1f_bih = (const float*)d_in[12];
  const float* l1f_bhh = (const float*)d_in[13];
  const float* l1b_Wih = (const float*)d_in[14];
  const float* l1b_Whh = (const float*)d_in[15];
  const float* l1b_bih = (const float*)d_in[16];
  const float* l1b_bhh = (const float*)d_in[17];
  const float* W_out = (const float*)d_in[18];
  const float* b_out = (const float*)d_in[19];
  const float* transitions = (const float*)d_in[20];

  char* ws = (char*)d_ws;
  size_t off = 0;
  float* x0 = (float*)(ws + off);  off += (size_t)T_LEN * DMODEL * 4;          // 4MB
  float* xgf = (float*)(ws + off); off += (size_t)T_LEN * 1024 * 4;            // 8MB
  float* xgb = (float*)(ws + off); off += (size_t)T_LEN * 1024 * 4;            // 8MB
  float* x1 = (float*)(ws + off);  off += (size_t)T_LEN * DMODEL * 4;          // 4MB
  float* x2 = (float*)(ws + off);  off += (size_t)T_LEN * DMODEL * 4;          // 4MB
  float* feats = (float*)(ws + off); off += (size_t)T_LEN * NTAGS * 4;
  // align flags to 64B
  off = (off + 63) & ~(size_t)63;
  unsigned int* flags = (unsigned int*)(ws + off);  // 4 uints (2 per layer)
  off += 64;

  float* outf = (float*)d_out;

  // zero the sync counters (d_ws is re-poisoned before every launch)
  hipMemsetAsync(flags, 0, 64, stream);

  embed_k<<<dim3(T_LEN), dim3(128), 0, stream>>>(sent, emb, x0);

  gemm_xg_k<<<dim3(8, 16, 2), dim3(256), 0, stream>>>(
      x0, l0f_Wih, l0b_Wih, l0f_bih, l0b_bih, xgf, xgb);

  recur_k<<<dim3(8, 2), dim3(256), 0, stream>>>(
      xgf, xgb, l0f_Whh, l0b_Whh, l0f_bhh, l0b_bhh, x1, flags);

  gemm_xg_k<<<dim3(8, 16, 2), dim3(256), 0, stream>>>(
      x1, l1f_Wih, l1b_Wih, l1f_bih, l1b_bih, xgf, xgb);

  recur_k<<<dim3(8, 2), dim3(256), 0, stream>>>(
      xgf, xgb, l1f_Whh, l1b_Whh, l1f_bhh, l1b_bhh, x2, flags + 2);

  proj_k<<<dim3(T_LEN), dim3(256), 0, stream>>>(x2, W_out, b_out, feats);

  viterbi_k<<<dim3(1), dim3(64), 0, stream>>>(feats, transitions, outf);
}

// Round 3
// 13714.151 us; speedup vs baseline: 1.1325x; 1.1325x over previous
//
#include <hip/hip_runtime.h>
#include <math.h>

// ---------------------------------------------------------------------------
// BiLSTM-CRF tagger on MI355X.
//   T=2048, D=512, H=512, HD=256, L=2, NTAGS=20, START=18, END=19
// Pipeline (all on `stream`):
//   1. embed gather            x0[T][512]
//   2. xg GEMM layer0 (f+b)    xg = x0 @ Wih^T + bih     [T][1024] per dir
//   3. recurrence layer0       x1[T][512]  (f cols 0..255, b cols 256..511)
//   4. xg GEMM layer1 (f+b)
//   5. recurrence layer1       x2[T][512]
//   6. projection              feats[T][20]
//   7. viterbi (fwd + backtrace) -> d_out[0]=score, d_out[1..2048]=path
//
// R1 lesson: 4096 threads spinning with agent-scope acquire loads generated
// 28.7 GB of flag-line fetches + continuous cache invalidation (recur_k was
// 7.3 ms, FETCH 28.7GB, VALUBusy 0.5%). R2: per-WG seq slots (plain release
// store, no RMW), ONE poller wave per WG (lanes 0..7 poll the 8 slots).
// R2 compile fixes: __builtin_amdgcn_fence for the acquire fence;
// (void)hipMemsetAsync.
// ---------------------------------------------------------------------------

#define T_LEN 2048
#define DMODEL 512
#define HD 256
#define NTAGS 20
#define START_TAG 18
#define END_TAG 19

__device__ __forceinline__ float fsig(float x) {
  return 1.0f / (1.0f + __expf(-x));
}
__device__ __forceinline__ float ftanh(float x) {
  float xc = fminf(15.0f, fmaxf(-15.0f, x));
  float e = __expf(2.0f * xc);
  return (e - 1.0f) / (e + 1.0f);
}

// ---------------------------------------------------------------------------
// 1. Embedding gather: x0[t][:] = emb[sentence[t]][:]
// ---------------------------------------------------------------------------
__global__ void embed_k(const int* __restrict__ sent,
                        const float* __restrict__ emb,
                        float* __restrict__ x0) {
  int t = blockIdx.x;
  int tid = threadIdx.x;  // 0..127
  int tok = sent[t];
  const float4* src = (const float4*)(emb + (size_t)tok * DMODEL);
  float4* dst = (float4*)(x0 + (size_t)t * DMODEL);
  dst[tid] = src[tid];
}

// ---------------------------------------------------------------------------
// 2. xg GEMM: out[t][n] = sum_k X[t][k] * W[n][k] + b[n]
//    X: [2048][512], W: [1024][512], out: [2048][1024]
// 128x128 block tile, 8x8 per thread, k-tile 16.
// grid: (N/128=8, M/128=16, 2 dirs), block 256
// ---------------------------------------------------------------------------
__global__ __launch_bounds__(256) void gemm_xg_k(
    const float* __restrict__ X,
    const float* __restrict__ Wf, const float* __restrict__ Wb,
    const float* __restrict__ bf, const float* __restrict__ bb,
    float* __restrict__ outf, float* __restrict__ outb) {
  int bx = blockIdx.x;   // N tile (0..7)
  int by = blockIdx.y;   // M tile (0..15)
  int dir = blockIdx.z;
  const float* W = dir ? Wb : Wf;
  const float* bias = dir ? bb : bf;
  float* out = dir ? outb : outf;

  __shared__ __align__(16) float Xs[16][132];
  __shared__ __align__(16) float Ws[16][132];

  int tid = threadIdx.x;
  int tx = tid & 15;   // 0..15 -> N
  int ty = tid >> 4;   // 0..15 -> M

  float acc[8][8];
#pragma unroll
  for (int i = 0; i < 8; i++)
#pragma unroll
    for (int j = 0; j < 8; j++) acc[i][j] = 0.0f;

  for (int kt = 0; kt < DMODEL / 16; kt++) {
    __syncthreads();
#pragma unroll
    for (int l = 0; l < 2; l++) {
      int fi = tid + l * 256;        // 0..511  (128 rows x 4 float4)
      int row = fi >> 2;
      int kq = fi & 3;
      float4 xv = *(const float4*)(X + (size_t)(by * 128 + row) * DMODEL + kt * 16 + kq * 4);
      Xs[kq * 4 + 0][row] = xv.x;
      Xs[kq * 4 + 1][row] = xv.y;
      Xs[kq * 4 + 2][row] = xv.z;
      Xs[kq * 4 + 3][row] = xv.w;
      float4 wv = *(const float4*)(W + (size_t)(bx * 128 + row) * DMODEL + kt * 16 + kq * 4);
      Ws[kq * 4 + 0][row] = wv.x;
      Ws[kq * 4 + 1][row] = wv.y;
      Ws[kq * 4 + 2][row] = wv.z;
      Ws[kq * 4 + 3][row] = wv.w;
    }
    __syncthreads();
#pragma unroll
    for (int k = 0; k < 16; k++) {
      float4 a0 = *(const float4*)&Xs[k][ty * 4];
      float4 a1 = *(const float4*)&Xs[k][64 + ty * 4];
      float4 b0 = *(const float4*)&Ws[k][tx * 4];
      float4 b1 = *(const float4*)&Ws[k][64 + tx * 4];
      float a[8] = {a0.x, a0.y, a0.z, a0.w, a1.x, a1.y, a1.z, a1.w};
      float b[8] = {b0.x, b0.y, b0.z, b0.w, b1.x, b1.y, b1.z, b1.w};
#pragma unroll
      for (int i = 0; i < 8; i++)
#pragma unroll
        for (int j = 0; j < 8; j++) acc[i][j] += a[i] * b[j];
    }
  }

  float4 bv0 = *(const float4*)(bias + bx * 128 + tx * 4);
  float4 bv1 = *(const float4*)(bias + bx * 128 + 64 + tx * 4);
  float bb8[8] = {bv0.x, bv0.y, bv0.z, bv0.w, bv1.x, bv1.y, bv1.z, bv1.w};
#pragma unroll
  for (int i = 0; i < 8; i++) {
    int row = by * 128 + ((i < 4) ? (ty * 4 + i) : (64 + ty * 4 + (i - 4)));
    float4 o0 = {acc[i][0] + bb8[0], acc[i][1] + bb8[1], acc[i][2] + bb8[2], acc[i][3] + bb8[3]};
    float4 o1 = {acc[i][4] + bb8[4], acc[i][5] + bb8[5], acc[i][6] + bb8[6], acc[i][7] + bb8[7]};
    *(float4*)(out + (size_t)row * 1024 + bx * 128 + tx * 4) = o0;
    *(float4*)(out + (size_t)row * 1024 + bx * 128 + 64 + tx * 4) = o1;
  }
}

// ---------------------------------------------------------------------------
// 3/5. Recurrence. grid: (8 chunks, 2 dirs), block 256.
// WG (kc,dir) owns gate rows {g*256 + kc*32 + kl : g in 0..3, kl in 0..31}.
// Weights in VGPRs (32 float4 per thread). Per step:
//   z = Whh-slab . h  (h broadcast from LDS) -> pair-reduce -> + xg + bhh
//   gate threads (tid<32) update c, write h chunk to x_next[t]
//   release: __syncthreads (drains vmcnt) -> tid0 threadfence + release-store
//            seq[kc] = it+1 (per-WG slot, own 128B line — no RMW, no sharing)
//   acquire: wave 0 lanes 0..7 poll the 8 slots; wave exits when all lanes
//            see >= it+1 (exec-mask convergence = "all"); barrier; acquire
//            fence by all threads; reload h.
// ---------------------------------------------------------------------------
__global__ __launch_bounds__(256) void recur_k(
    const float* __restrict__ xg_f, const float* __restrict__ xg_b,
    const float* __restrict__ Whh_f, const float* __restrict__ Whh_b,
    const float* __restrict__ bhh_f, const float* __restrict__ bhh_b,
    float* __restrict__ xnext, unsigned int* __restrict__ seqbase) {
  int kc = blockIdx.x;          // 0..7
  int dir = blockIdx.y;         // 0=f, 1=b
  int tid = threadIdx.x;        // 0..255

  const float* Whh = dir ? Whh_b : Whh_f;
  const float* bhh = dir ? bhh_b : bhh_f;
  const float* xg = dir ? xg_b : xg_f;
  // per-direction bank of 8 slots, 32 uints (128B) apart
  unsigned int* seq = seqbase + (size_t)dir * 8 * 32;

  int r = tid >> 1;             // local row 0..127
  int half = tid & 1;           // which 128-col half
  int g = r >> 5;               // gate 0..3 (i,f,g,o)
  int kl = r & 31;
  int grow = g * 256 + kc * 32 + kl;  // global gate row 0..1023

  // load weight slab into registers
  float4 Wv[32];
  const float4* wrow = (const float4*)(Whh + (size_t)grow * HD + half * 128);
#pragma unroll
  for (int j = 0; j < 32; j++) Wv[j] = wrow[j];
  float bias = bhh[grow];

  __shared__ __align__(16) float hbuf[HD];   // h_{t-1}
  __shared__ float zbuf[128];
  hbuf[tid] = 0.0f;   // tid 0..255 covers HD=256
  __syncthreads();

  float c = 0.0f;  // cell state, used by tid<32

#pragma unroll 1
  for (int it = 0; it < T_LEN; ++it) {
    int t = dir ? (T_LEN - 1 - it) : it;

    // prefetch xg early (even lanes only; consumed after the FMA loop)
    float xgv = 0.0f;
    if (!half) xgv = xg[(size_t)t * 1024 + grow];

    const float4* h4 = (const float4*)hbuf + half * 32;
    float4 acc = {0.f, 0.f, 0.f, 0.f};
#pragma unroll
    for (int j = 0; j < 32; j++) {
      float4 hv = h4[j];
      acc.x += Wv[j].x * hv.x;
      acc.y += Wv[j].y * hv.y;
      acc.z += Wv[j].z * hv.z;
      acc.w += Wv[j].w * hv.w;
    }
    float s = (acc.x + acc.y) + (acc.z + acc.w);
    s += __shfl_xor(s, 1, 64);   // combine the two halves of the row
    if (!half) zbuf[r] = s + xgv + bias;
    __syncthreads();

    if (tid < 32) {
      float zi = zbuf[tid];
      float zf = zbuf[32 + tid];
      float zg = zbuf[64 + tid];
      float zo = zbuf[96 + tid];
      c = fsig(zf) * c + fsig(zi) * ftanh(zg);
      float h = fsig(zo) * ftanh(c);
      xnext[(size_t)t * DMODEL + dir * HD + kc * 32 + tid] = h;
    }
    __syncthreads();  // gate stores complete (vmcnt drained) before release

    unsigned int target = (unsigned)(it + 1);
    if (tid == 0) {
      __threadfence();  // make h-chunk visible at device scope
      __hip_atomic_store(&seq[kc * 32], target, __ATOMIC_RELEASE,
                         __HIP_MEMORY_SCOPE_AGENT);
    }
    // one wave polls; loop is self-throttled by acquire-load latency
    if (tid < 64) {
      if (tid < 8) {
        while (__hip_atomic_load(&seq[tid * 32], __ATOMIC_ACQUIRE,
                                 __HIP_MEMORY_SCOPE_AGENT) < target) {
        }
      }
    }
    __syncthreads();
    // propagate the acquire to all threads before they read h
    __builtin_amdgcn_fence(__ATOMIC_ACQUIRE, "agent");

    // reload full h_t into LDS for next step
    if (tid < 64) {
      ((float4*)hbuf)[tid] = ((const float4*)(xnext + (size_t)t * DMODEL + dir * HD))[tid];
    }
    __syncthreads();
  }
}

// ---------------------------------------------------------------------------
// 6. Projection: feats[t][n] = x2[t][:] . W_out[n][:] + b_out[n]
// ---------------------------------------------------------------------------
__global__ void proj_k(const float* __restrict__ x2,
                       const float* __restrict__ Wo,
                       const float* __restrict__ bo,
                       float* __restrict__ feats) {
  int t = blockIdx.x;
  int tid = threadIdx.x;
  int n = tid & 31;
  int seg = tid >> 5;   // 0..7
  __shared__ float red[8][32];
  float s = 0.0f;
  if (n < NTAGS) {
    const float* xr = x2 + (size_t)t * DMODEL + seg * 64;
    const float* wr = Wo + (size_t)n * DMODEL + seg * 64;
#pragma unroll
    for (int j = 0; j < 64; j++) s += xr[j] * wr[j];
  }
  red[seg][n] = s;
  __syncthreads();
  if (tid < NTAGS) {
    float tot = bo[tid];
#pragma unroll
    for (int k = 0; k < 8; k++) tot += red[k][tid];
    feats[(size_t)t * NTAGS + tid] = tot;
  }
}

// ---------------------------------------------------------------------------
// 7. Viterbi: single block, 64 threads (one wave).
// ---------------------------------------------------------------------------
__global__ void viterbi_k(const float* __restrict__ feats,
                          const float* __restrict__ tr,
                          float* __restrict__ out) {
  __shared__ float v[NTAGS];
  __shared__ unsigned char bp[T_LEN * NTAGS];  // 40KB
  __shared__ float term[NTAGS];
  int tid = threadIdx.x;

  float trrow[NTAGS];
  if (tid < NTAGS) {
#pragma unroll
    for (int p = 0; p < NTAGS; p++) trrow[p] = tr[tid * NTAGS + p];
    v[tid] = (tid == START_TAG) ? 0.0f : -10000.0f;
  }
  __syncthreads();

#pragma unroll 1
  for (int t = 0; t < T_LEN; t++) {
    float fv = 0.0f;
    if (tid < NTAGS) fv = feats[(size_t)t * NTAGS + tid];
    float best = -3.4e38f;
    int arg = 0;
    if (tid < NTAGS) {
#pragma unroll
      for (int p = 0; p < NTAGS; p++) {
        float sc = v[p] + trrow[p];
        if (sc > best) { best = sc; arg = p; }
      }
      bp[t * NTAGS + tid] = (unsigned char)arg;
    }
    __syncthreads();
    if (tid < NTAGS) v[tid] = best + fv;
    __syncthreads();
  }

  if (tid < NTAGS) term[tid] = v[tid] + tr[END_TAG * NTAGS + tid];
  __syncthreads();
  if (tid == 0) {
    float bs = term[0];
    int bi = 0;
    for (int p = 1; p < NTAGS; p++) {
      if (term[p] > bs) { bs = term[p]; bi = p; }
    }
    out[0] = bs;
    int tag = bi;
    for (int t = T_LEN - 1; t >= 0; t--) {
      out[1 + t] = (float)tag;
      tag = bp[t * NTAGS + tag];
    }
  }
}

// ---------------------------------------------------------------------------
// Launch
// ---------------------------------------------------------------------------
extern "C" void kernel_launch(void* const* d_in, const int* in_sizes, int n_in,
                              void* d_out, int out_size, void* d_ws, size_t ws_size,
                              hipStream_t stream) {
  const int* sent = (const int*)d_in[0];
  const float* emb = (const float*)d_in[1];
  const float* l0f_Wih = (const float*)d_in[2];
  const float* l0f_Whh = (const float*)d_in[3];
  const float* l0f_bih = (const float*)d_in[4];
  const float* l0f_bhh = (const float*)d_in[5];
  const float* l0b_Wih = (const float*)d_in[6];
  const float* l0b_Whh = (const float*)d_in[7];
  const float* l0b_bih = (const float*)d_in[8];
  const float* l0b_bhh = (const float*)d_in[9];
  const float* l1f_Wih = (const float*)d_in[10];
  const float* l1f_Whh = (const float*)d_in[11];
  const float* l1f_bih = (const float*)d_in[12];
  const float* l1f_bhh = (const float*)d_in[13];
  const float* l1b_Wih = (const float*)d_in[14];
  const float* l1b_Whh = (const float*)d_in[15];
  const float* l1b_bih = (const float*)d_in[16];
  const float* l1b_bhh = (const float*)d_in[17];
  const float* W_out = (const float*)d_in[18];
  const float* b_out = (const float*)d_in[19];
  const float* transitions = (const float*)d_in[20];

  char* ws = (char*)d_ws;
  size_t off = 0;
  float* x0 = (float*)(ws + off);  off += (size_t)T_LEN * DMODEL * 4;          // 4MB
  float* xgf = (float*)(ws + off); off += (size_t)T_LEN * 1024 * 4;            // 8MB
  float* xgb = (float*)(ws + off); off += (size_t)T_LEN * 1024 * 4;            // 8MB
  float* x1 = (float*)(ws + off);  off += (size_t)T_LEN * DMODEL * 4;          // 4MB
  float* x2 = (float*)(ws + off);  off += (size_t)T_LEN * DMODEL * 4;          // 4MB
  float* feats = (float*)(ws + off); off += (size_t)T_LEN * NTAGS * 4;
  // seq slots: 2 layers x 2 dirs x 8 slots x 128B, 128B-aligned
  off = (off + 127) & ~(size_t)127;
  unsigned int* seq0 = (unsigned int*)(ws + off);   // layer0: 2*8 slots
  off += 2 * 8 * 128;
  unsigned int* seq1 = (unsigned int*)(ws + off);   // layer1
  off += 2 * 8 * 128;

  float* outf = (float*)d_out;

  // zero all sync slots (d_ws is re-poisoned to 0xAA before every launch)
  (void)hipMemsetAsync(seq0, 0, 4 * 8 * 128, stream);

  embed_k<<<dim3(T_LEN), dim3(128), 0, stream>>>(sent, emb, x0);

  gemm_xg_k<<<dim3(8, 16, 2), dim3(256), 0, stream>>>(
      x0, l0f_Wih, l0b_Wih, l0f_bih, l0b_bih, xgf, xgb);

  recur_k<<<dim3(8, 2), dim3(256), 0, stream>>>(
      xgf, xgb, l0f_Whh, l0b_Whh, l0f_bhh, l0b_bhh, x1, seq0);

  gemm_xg_k<<<dim3(8, 16, 2), dim3(256), 0, stream>>>(
      x1, l1f_Wih, l1b_Wih, l1f_bih, l1b_bih, xgf, xgb);

  recur_k<<<dim3(8, 2), dim3(256), 0, stream>>>(
      xgf, xgb, l1f_Whh, l1b_Whh, l1f_bhh, l1b_bhh, x2, seq1);

  proj_k<<<dim3(T_LEN), dim3(256), 0, stream>>>(x2, W_out, b_out, feats);

  viterbi_k<<<dim3(1), dim3(64), 0, stream>>>(feats, transitions, outf);
}

// Round 4
// 8035.922 us; speedup vs baseline: 1.9328x; 1.7066x over previous
//
#include <hip/hip_runtime.h>
#include <math.h>

// ---------------------------------------------------------------------------
// BiLSTM-CRF tagger on MI355X.
//   T=2048, D=512, H=512, HD=256, L=2, NTAGS=20, START=18, END=19
// Pipeline (all on `stream`):
//   1. embed gather            x0[T][512]
//   2. xg GEMM layer0 (f+b)    xg = x0 @ Wih^T + bih     [T][1024] per dir
//   3. recurrence layer0       x1[T][512]  (f cols 0..255, b cols 256..511)
//   4. xg GEMM layer1 (f+b)
//   5. recurrence layer1       x2[T][512]
//   6. projection              feats[T][20]
//   7. viterbi (fwd + backtrace) -> d_out[0]=score, d_out[1..2048]=path
//
// R1: 4096 spinning acquire loads -> 7.3ms recur. R3: 1 poll wave + per-WG
// release slots -> only 6.2ms: the cost is NOT traffic (FETCH=42MB), it's the
// agent-scope fence protocol itself. On gfx950 per-XCD L2s are non-coherent,
// so every release fence = vmcnt drain + L2 writeback, every acquire = L2
// invalidate + IF$ round trip; ~3 serialized IF$ round trips + 2 cache flush
// ops per step = ~7270 cyc/step.
// R4: fence-free seqlock handoff. h values travel THROUGH relaxed 64-bit
// agent atomics as (tag<<32 | float_bits). Single atomic word => payload and
// tag indivisible, no ordering required, zero fences, L2 stays warm.
// Double-buffered by step parity. Safety: producer overwrites set[p] at step
// it+2 only after its poll at it+1 saw every WG's tag it+2 in set[1-p]; a WG
// publishes tag it+2 only after (program order + __syncthreads) finishing its
// reads of set[p] at step it. So no slot is overwritten while readable, and
// no reader can miss its tag.
// ---------------------------------------------------------------------------

#define T_LEN 2048
#define DMODEL 512
#define HD 256
#define NTAGS 20
#define START_TAG 18
#define END_TAG 19

__device__ __forceinline__ float fsig(float x) {
  return 1.0f / (1.0f + __expf(-x));
}
__device__ __forceinline__ float ftanh(float x) {
  float xc = fminf(15.0f, fmaxf(-15.0f, x));
  float e = __expf(2.0f * xc);
  return (e - 1.0f) / (e + 1.0f);
}

// ---------------------------------------------------------------------------
// 1. Embedding gather: x0[t][:] = emb[sentence[t]][:]
// ---------------------------------------------------------------------------
__global__ void embed_k(const int* __restrict__ sent,
                        const float* __restrict__ emb,
                        float* __restrict__ x0) {
  int t = blockIdx.x;
  int tid = threadIdx.x;  // 0..127
  int tok = sent[t];
  const float4* src = (const float4*)(emb + (size_t)tok * DMODEL);
  float4* dst = (float4*)(x0 + (size_t)t * DMODEL);
  dst[tid] = src[tid];
}

// ---------------------------------------------------------------------------
// 2. xg GEMM: out[t][n] = sum_k X[t][k] * W[n][k] + b[n]
//    X: [2048][512], W: [1024][512], out: [2048][1024]
// 128x128 block tile, 8x8 per thread, k-tile 16.
// grid: (N/128=8, M/128=16, 2 dirs), block 256
// ---------------------------------------------------------------------------
__global__ __launch_bounds__(256) void gemm_xg_k(
    const float* __restrict__ X,
    const float* __restrict__ Wf, const float* __restrict__ Wb,
    const float* __restrict__ bf, const float* __restrict__ bb,
    float* __restrict__ outf, float* __restrict__ outb) {
  int bx = blockIdx.x;   // N tile (0..7)
  int by = blockIdx.y;   // M tile (0..15)
  int dir = blockIdx.z;
  const float* W = dir ? Wb : Wf;
  const float* bias = dir ? bb : bf;
  float* out = dir ? outb : outf;

  __shared__ __align__(16) float Xs[16][132];
  __shared__ __align__(16) float Ws[16][132];

  int tid = threadIdx.x;
  int tx = tid & 15;   // 0..15 -> N
  int ty = tid >> 4;   // 0..15 -> M

  float acc[8][8];
#pragma unroll
  for (int i = 0; i < 8; i++)
#pragma unroll
    for (int j = 0; j < 8; j++) acc[i][j] = 0.0f;

  for (int kt = 0; kt < DMODEL / 16; kt++) {
    __syncthreads();
#pragma unroll
    for (int l = 0; l < 2; l++) {
      int fi = tid + l * 256;        // 0..511  (128 rows x 4 float4)
      int row = fi >> 2;
      int kq = fi & 3;
      float4 xv = *(const float4*)(X + (size_t)(by * 128 + row) * DMODEL + kt * 16 + kq * 4);
      Xs[kq * 4 + 0][row] = xv.x;
      Xs[kq * 4 + 1][row] = xv.y;
      Xs[kq * 4 + 2][row] = xv.z;
      Xs[kq * 4 + 3][row] = xv.w;
      float4 wv = *(const float4*)(W + (size_t)(bx * 128 + row) * DMODEL + kt * 16 + kq * 4);
      Ws[kq * 4 + 0][row] = wv.x;
      Ws[kq * 4 + 1][row] = wv.y;
      Ws[kq * 4 + 2][row] = wv.z;
      Ws[kq * 4 + 3][row] = wv.w;
    }
    __syncthreads();
#pragma unroll
    for (int k = 0; k < 16; k++) {
      float4 a0 = *(const float4*)&Xs[k][ty * 4];
      float4 a1 = *(const float4*)&Xs[k][64 + ty * 4];
      float4 b0 = *(const float4*)&Ws[k][tx * 4];
      float4 b1 = *(const float4*)&Ws[k][64 + tx * 4];
      float a[8] = {a0.x, a0.y, a0.z, a0.w, a1.x, a1.y, a1.z, a1.w};
      float b[8] = {b0.x, b0.y, b0.z, b0.w, b1.x, b1.y, b1.z, b1.w};
#pragma unroll
      for (int i = 0; i < 8; i++)
#pragma unroll
        for (int j = 0; j < 8; j++) acc[i][j] += a[i] * b[j];
    }
  }

  float4 bv0 = *(const float4*)(bias + bx * 128 + tx * 4);
  float4 bv1 = *(const float4*)(bias + bx * 128 + 64 + tx * 4);
  float bb8[8] = {bv0.x, bv0.y, bv0.z, bv0.w, bv1.x, bv1.y, bv1.z, bv1.w};
#pragma unroll
  for (int i = 0; i < 8; i++) {
    int row = by * 128 + ((i < 4) ? (ty * 4 + i) : (64 + ty * 4 + (i - 4)));
    float4 o0 = {acc[i][0] + bb8[0], acc[i][1] + bb8[1], acc[i][2] + bb8[2], acc[i][3] + bb8[3]};
    float4 o1 = {acc[i][4] + bb8[4], acc[i][5] + bb8[5], acc[i][6] + bb8[6], acc[i][7] + bb8[7]};
    *(float4*)(out + (size_t)row * 1024 + bx * 128 + tx * 4) = o0;
    *(float4*)(out + (size_t)row * 1024 + bx * 128 + 64 + tx * 4) = o1;
  }
}

// ---------------------------------------------------------------------------
// 3/5. Recurrence. grid: (8 chunks, 2 dirs), block 256.
// WG (kc,dir) owns gate rows {g*256 + kc*32 + kl : g in 0..3, kl in 0..31}.
// Weights in VGPRs (32 float4 per thread). Per step:
//   z = Whh-slab . h (h from LDS) -> shfl pair-reduce -> + xg + bhh
//   gate threads (tid<32): c,h update; h -> xnext[t] (plain store; consumed
//     by the NEXT KERNEL, kernel boundary provides the sync), h -> own LDS
//     slot, and (tag|bits) -> hcomm[dir][p][chunk] via RELAXED agent atomic.
//   every thread polls hcomm[dir][p][tid] (tid outside own chunk) with
//     relaxed 64-bit atomic loads until tag==it+1; writes value to LDS.
//   No fences anywhere.
// ---------------------------------------------------------------------------
__global__ __launch_bounds__(256) void recur_k(
    const float* __restrict__ xg_f, const float* __restrict__ xg_b,
    const float* __restrict__ Whh_f, const float* __restrict__ Whh_b,
    const float* __restrict__ bhh_f, const float* __restrict__ bhh_b,
    float* __restrict__ xnext, unsigned long long* __restrict__ hcomm_base) {
  int kc = blockIdx.x;          // 0..7
  int dir = blockIdx.y;         // 0=f, 1=b
  int tid = threadIdx.x;        // 0..255

  const float* Whh = dir ? Whh_b : Whh_f;
  const float* bhh = dir ? bhh_b : bhh_f;
  const float* xg = dir ? xg_b : xg_f;
  // per-direction region: 2 parity sets x 256 entries
  unsigned long long* hcomm = hcomm_base + (size_t)dir * 2 * HD;

  int r = tid >> 1;             // local row 0..127
  int half = tid & 1;           // which 128-col half
  int g = r >> 5;               // gate 0..3 (i,f,g,o)
  int kl = r & 31;
  int grow = g * 256 + kc * 32 + kl;  // global gate row 0..1023

  // load weight slab into registers
  float4 Wv[32];
  const float4* wrow = (const float4*)(Whh + (size_t)grow * HD + half * 128);
#pragma unroll
  for (int j = 0; j < 32; j++) Wv[j] = wrow[j];
  float bias = bhh[grow];

  __shared__ __align__(16) float hbuf[HD];   // h_{t-1}
  __shared__ float zbuf[128];
  hbuf[tid] = 0.0f;   // tid 0..255 covers HD=256
  __syncthreads();

  float c = 0.0f;  // cell state, used by tid<32
  bool is_remote = ((tid >> 5) != kc);  // this thread polls entry `tid`

#pragma unroll 1
  for (int it = 0; it < T_LEN; ++it) {
    int t = dir ? (T_LEN - 1 - it) : it;
    int p = it & 1;
    unsigned int tag = (unsigned)(it + 1);

    // prefetch xg early (even lanes only; consumed after the FMA loop)
    float xgv = 0.0f;
    if (!half) xgv = xg[(size_t)t * 1024 + grow];

    const float4* h4 = (const float4*)hbuf + half * 32;
    float4 acc = {0.f, 0.f, 0.f, 0.f};
#pragma unroll
    for (int j = 0; j < 32; j++) {
      float4 hv = h4[j];
      acc.x += Wv[j].x * hv.x;
      acc.y += Wv[j].y * hv.y;
      acc.z += Wv[j].z * hv.z;
      acc.w += Wv[j].w * hv.w;
    }
    float s = (acc.x + acc.y) + (acc.z + acc.w);
    s += __shfl_xor(s, 1, 64);   // combine the two halves of the row
    if (!half) zbuf[r] = s + xgv + bias;
    __syncthreads();             // zbuf ready; hbuf reads of h_{t-1} done

    if (tid < 32) {
      float zi = zbuf[tid];
      float zf = zbuf[32 + tid];
      float zg = zbuf[64 + tid];
      float zo = zbuf[96 + tid];
      c = fsig(zf) * c + fsig(zi) * ftanh(zg);
      float h = fsig(zo) * ftanh(c);
      // feed next pipeline stage (sync'd by kernel boundary)
      xnext[(size_t)t * DMODEL + dir * HD + kc * 32 + tid] = h;
      // own chunk straight into LDS
      hbuf[kc * 32 + tid] = h;
      // publish (tag | bits) to peers — single 64b relaxed atomic, no fence
      union { float f; unsigned u; } cv;
      cv.f = h;
      __hip_atomic_store(&hcomm[p * HD + kc * 32 + tid],
                         ((unsigned long long)tag << 32) | cv.u,
                         __ATOMIC_RELAXED, __HIP_MEMORY_SCOPE_AGENT);
    }
    if (is_remote) {
      unsigned long long v;
      do {
        v = __hip_atomic_load(&hcomm[p * HD + tid], __ATOMIC_RELAXED,
                              __HIP_MEMORY_SCOPE_AGENT);
      } while ((unsigned)(v >> 32) != tag);
      union { unsigned u; float f; } cv;
      cv.u = (unsigned)v;
      hbuf[tid] = cv.f;
    }
    __syncthreads();             // full h_t assembled in LDS
  }
}

// ---------------------------------------------------------------------------
// 6. Projection: feats[t][n] = x2[t][:] . W_out[n][:] + b_out[n]
// ---------------------------------------------------------------------------
__global__ void proj_k(const float* __restrict__ x2,
                       const float* __restrict__ Wo,
                       const float* __restrict__ bo,
                       float* __restrict__ feats) {
  int t = blockIdx.x;
  int tid = threadIdx.x;
  int n = tid & 31;
  int seg = tid >> 5;   // 0..7
  __shared__ float red[8][32];
  float s = 0.0f;
  if (n < NTAGS) {
    const float* xr = x2 + (size_t)t * DMODEL + seg * 64;
    const float* wr = Wo + (size_t)n * DMODEL + seg * 64;
#pragma unroll
    for (int j = 0; j < 64; j++) s += xr[j] * wr[j];
  }
  red[seg][n] = s;
  __syncthreads();
  if (tid < NTAGS) {
    float tot = bo[tid];
#pragma unroll
    for (int k = 0; k < 8; k++) tot += red[k][tid];
    feats[(size_t)t * NTAGS + tid] = tot;
  }
}

// ---------------------------------------------------------------------------
// 7. Viterbi: single block, 64 threads (one wave).
// ---------------------------------------------------------------------------
__global__ void viterbi_k(const float* __restrict__ feats,
                          const float* __restrict__ tr,
                          float* __restrict__ out) {
  __shared__ float v[NTAGS];
  __shared__ unsigned char bp[T_LEN * NTAGS];  // 40KB
  __shared__ float term[NTAGS];
  int tid = threadIdx.x;

  float trrow[NTAGS];
  if (tid < NTAGS) {
#pragma unroll
    for (int p = 0; p < NTAGS; p++) trrow[p] = tr[tid * NTAGS + p];
    v[tid] = (tid == START_TAG) ? 0.0f : -10000.0f;
  }
  __syncthreads();

#pragma unroll 1
  for (int t = 0; t < T_LEN; t++) {
    float fv = 0.0f;
    if (tid < NTAGS) fv = feats[(size_t)t * NTAGS + tid];
    float best = -3.4e38f;
    int arg = 0;
    if (tid < NTAGS) {
#pragma unroll
      for (int p = 0; p < NTAGS; p++) {
        float sc = v[p] + trrow[p];
        if (sc > best) { best = sc; arg = p; }
      }
      bp[t * NTAGS + tid] = (unsigned char)arg;
    }
    __syncthreads();
    if (tid < NTAGS) v[tid] = best + fv;
    __syncthreads();
  }

  if (tid < NTAGS) term[tid] = v[tid] + tr[END_TAG * NTAGS + tid];
  __syncthreads();
  if (tid == 0) {
    float bs = term[0];
    int bi = 0;
    for (int p = 1; p < NTAGS; p++) {
      if (term[p] > bs) { bs = term[p]; bi = p; }
    }
    out[0] = bs;
    int tag = bi;
    for (int t = T_LEN - 1; t >= 0; t--) {
      out[1 + t] = (float)tag;
      tag = bp[t * NTAGS + tag];
    }
  }
}

// ---------------------------------------------------------------------------
// Launch
// ---------------------------------------------------------------------------
extern "C" void kernel_launch(void* const* d_in, const int* in_sizes, int n_in,
                              void* d_out, int out_size, void* d_ws, size_t ws_size,
                              hipStream_t stream) {
  const int* sent = (const int*)d_in[0];
  const float* emb = (const float*)d_in[1];
  const float* l0f_Wih = (const float*)d_in[2];
  const float* l0f_Whh = (const float*)d_in[3];
  const float* l0f_bih = (const float*)d_in[4];
  const float* l0f_bhh = (const float*)d_in[5];
  const float* l0b_Wih = (const float*)d_in[6];
  const float* l0b_Whh = (const float*)d_in[7];
  const float* l0b_bih = (const float*)d_in[8];
  const float* l0b_bhh = (const float*)d_in[9];
  const float* l1f_Wih = (const float*)d_in[10];
  const float* l1f_Whh = (const float*)d_in[11];
  const float* l1f_bih = (const float*)d_in[12];
  const float* l1f_bhh = (const float*)d_in[13];
  const float* l1b_Wih = (const float*)d_in[14];
  const float* l1b_Whh = (const float*)d_in[15];
  const float* l1b_bih = (const float*)d_in[16];
  const float* l1b_bhh = (const float*)d_in[17];
  const float* W_out = (const float*)d_in[18];
  const float* b_out = (const float*)d_in[19];
  const float* transitions = (const float*)d_in[20];

  char* ws = (char*)d_ws;
  size_t off = 0;
  float* x0 = (float*)(ws + off);  off += (size_t)T_LEN * DMODEL * 4;          // 4MB
  float* xgf = (float*)(ws + off); off += (size_t)T_LEN * 1024 * 4;            // 8MB
  float* xgb = (float*)(ws + off); off += (size_t)T_LEN * 1024 * 4;            // 8MB
  float* x1 = (float*)(ws + off);  off += (size_t)T_LEN * DMODEL * 4;          // 4MB
  float* x2 = (float*)(ws + off);  off += (size_t)T_LEN * DMODEL * 4;          // 4MB
  float* feats = (float*)(ws + off); off += (size_t)T_LEN * NTAGS * 4;
  // hcomm: [layer][dir][parity][256] x 8B = 16KB, 128B-aligned
  off = (off + 127) & ~(size_t)127;
  unsigned long long* hcomm0 = (unsigned long long*)(ws + off);  // layer0
  off += (size_t)2 * 2 * HD * 8;
  unsigned long long* hcomm1 = (unsigned long long*)(ws + off);  // layer1
  off += (size_t)2 * 2 * HD * 8;

  float* outf = (float*)d_out;

  // zero hcomm tags (d_ws is re-poisoned to 0xAA before every launch;
  // 0xAAAAAAAA would never match any expected tag -> must clear)
  (void)hipMemsetAsync(hcomm0, 0, (size_t)2 * 2 * 2 * HD * 8, stream);

  embed_k<<<dim3(T_LEN), dim3(128), 0, stream>>>(sent, emb, x0);

  gemm_xg_k<<<dim3(8, 16, 2), dim3(256), 0, stream>>>(
      x0, l0f_Wih, l0b_Wih, l0f_bih, l0b_bih, xgf, xgb);

  recur_k<<<dim3(8, 2), dim3(256), 0, stream>>>(
      xgf, xgb, l0f_Whh, l0b_Whh, l0f_bhh, l0b_bhh, x1, hcomm0);

  gemm_xg_k<<<dim3(8, 16, 2), dim3(256), 0, stream>>>(
      x1, l1f_Wih, l1b_Wih, l1f_bih, l1b_bih, xgf, xgb);

  recur_k<<<dim3(8, 2), dim3(256), 0, stream>>>(
      xgf, xgb, l1f_Whh, l1b_Whh, l1f_bhh, l1b_bhh, x2, hcomm1);

  proj_k<<<dim3(T_LEN), dim3(256), 0, stream>>>(x2, W_out, b_out, feats);

  viterbi_k<<<dim3(1), dim3(64), 0, stream>>>(feats, transitions, outf);
}

// Round 6
// 8027.233 us; speedup vs baseline: 1.9349x; 1.0011x over previous
//
#include <hip/hip_runtime.h>
#include <math.h>

// ---------------------------------------------------------------------------
// BiLSTM-CRF tagger on MI355X.
//   T=2048, D=512, H=512, HD=256, L=2, NTAGS=20, START=18, END=19
//
// R1: 4096 spinning agent-acquire loads -> 7.3ms recur (cache-inv storm).
// R3: release/acquire slots -> 6.2ms: agent fence protocol (L2 wb+inv) is
//     the per-step cost on non-coherent XCDs.
// R4: fence-free seqlock (tag<<32|payload in one relaxed 64b agent atomic),
//     parity double-buffer -> 3.58ms. Remaining ~4200cy/step = 2 serialized
//     Infinity-Cache round trips (agent atomics bypass the per-XCD L2).
// R5: sc0-load seqlock on a same-XCD octet -> HANG. Lesson: sc0 on a load is
//     a *scope* hint; it can be served from the consumer's own L1 -> stale
//     spin forever.
// R6: correct L2-read primitive: atomic RMW w/ return (global_atomic_add_x2
//     +0, sc0=return-old) executes AT the XCD L2, never L1. Producer uses a
//     plain write-through store. Runtime coherence PROBE (bounded spin) on
//     the elected octet decides use_l2; votes exchanged via the proven
//     agent path; fallback = R4 seqlock. No unbounded wait on an unproven
//     path => deadlock-free.
// ---------------------------------------------------------------------------

#define T_LEN 2048
#define DMODEL 512
#define HD 256
#define NTAGS 20
#define START_TAG 18
#define END_TAG 19
#define NCAND 128   // candidate WGs per direction for the election

__device__ __forceinline__ float fsig(float x) {
  return 1.0f / (1.0f + __expf(-x));
}
__device__ __forceinline__ float ftanh(float x) {
  float xc = fminf(15.0f, fmaxf(-15.0f, x));
  float e = __expf(2.0f * xc);
  return (e - 1.0f) / (e + 1.0f);
}

// Read current L2 content (bypasses L1 by construction: atomic RMW executes
// at the coherence point). sc0 = return old value on gfx950.
__device__ __forceinline__ unsigned long long rd_l2(unsigned long long* p) {
  unsigned long long old;
  unsigned long long zero = 0;
  asm volatile("global_atomic_add_x2 %0, %1, %2, off sc0\n\ts_waitcnt vmcnt(0)"
               : "=&v"(old)
               : "v"(p), "v"(zero)
               : "memory");
  return old;
}
// Producer publish: plain store; CDNA L1 is write-through so this reaches the
// XCD-shared L2 without any cache-maintenance ops.
__device__ __forceinline__ void pub_l2(unsigned long long* p,
                                       unsigned long long v) {
  *(volatile unsigned long long*)p = v;
}

// ---------------------------------------------------------------------------
// 1. Embedding gather: x0[t][:] = emb[sentence[t]][:]
// ---------------------------------------------------------------------------
__global__ void embed_k(const int* __restrict__ sent,
                        const float* __restrict__ emb,
                        float* __restrict__ x0) {
  int t = blockIdx.x;
  int tid = threadIdx.x;  // 0..127
  int tok = sent[t];
  const float4* src = (const float4*)(emb + (size_t)tok * DMODEL);
  float4* dst = (float4*)(x0 + (size_t)t * DMODEL);
  dst[tid] = src[tid];
}

// ---------------------------------------------------------------------------
// 2. xg GEMM: out[t][n] = sum_k X[t][k] * W[n][k] + b[n]
//    X: [2048][512], W: [1024][512], out: [2048][1024]
// 128x128 block tile, 8x8 per thread, k-tile 16.
// grid: (N/128=8, M/128=16, 2 dirs), block 256
// ---------------------------------------------------------------------------
__global__ __launch_bounds__(256) void gemm_xg_k(
    const float* __restrict__ X,
    const float* __restrict__ Wf, const float* __restrict__ Wb,
    const float* __restrict__ bf, const float* __restrict__ bb,
    float* __restrict__ outf, float* __restrict__ outb) {
  int bx = blockIdx.x;   // N tile (0..7)
  int by = blockIdx.y;   // M tile (0..15)
  int dir = blockIdx.z;
  const float* W = dir ? Wb : Wf;
  const float* bias = dir ? bb : bf;
  float* out = dir ? outb : outf;

  __shared__ __align__(16) float Xs[16][132];
  __shared__ __align__(16) float Ws[16][132];

  int tid = threadIdx.x;
  int tx = tid & 15;   // 0..15 -> N
  int ty = tid >> 4;   // 0..15 -> M

  float acc[8][8];
#pragma unroll
  for (int i = 0; i < 8; i++)
#pragma unroll
    for (int j = 0; j < 8; j++) acc[i][j] = 0.0f;

  for (int kt = 0; kt < DMODEL / 16; kt++) {
    __syncthreads();
#pragma unroll
    for (int l = 0; l < 2; l++) {
      int fi = tid + l * 256;        // 0..511  (128 rows x 4 float4)
      int row = fi >> 2;
      int kq = fi & 3;
      float4 xv = *(const float4*)(X + (size_t)(by * 128 + row) * DMODEL + kt * 16 + kq * 4);
      Xs[kq * 4 + 0][row] = xv.x;
      Xs[kq * 4 + 1][row] = xv.y;
      Xs[kq * 4 + 2][row] = xv.z;
      Xs[kq * 4 + 3][row] = xv.w;
      float4 wv = *(const float4*)(W + (size_t)(bx * 128 + row) * DMODEL + kt * 16 + kq * 4);
      Ws[kq * 4 + 0][row] = wv.x;
      Ws[kq * 4 + 1][row] = wv.y;
      Ws[kq * 4 + 2][row] = wv.z;
      Ws[kq * 4 + 3][row] = wv.w;
    }
    __syncthreads();
#pragma unroll
    for (int k = 0; k < 16; k++) {
      float4 a0 = *(const float4*)&Xs[k][ty * 4];
      float4 a1 = *(const float4*)&Xs[k][64 + ty * 4];
      float4 b0 = *(const float4*)&Ws[k][tx * 4];
      float4 b1 = *(const float4*)&Ws[k][64 + tx * 4];
      float a[8] = {a0.x, a0.y, a0.z, a0.w, a1.x, a1.y, a1.z, a1.w};
      float b[8] = {b0.x, b0.y, b0.z, b0.w, b1.x, b1.y, b1.z, b1.w};
#pragma unroll
      for (int i = 0; i < 8; i++)
#pragma unroll
        for (int j = 0; j < 8; j++) acc[i][j] += a[i] * b[j];
    }
  }

  float4 bv0 = *(const float4*)(bias + bx * 128 + tx * 4);
  float4 bv1 = *(const float4*)(bias + bx * 128 + 64 + tx * 4);
  float bb8[8] = {bv0.x, bv0.y, bv0.z, bv0.w, bv1.x, bv1.y, bv1.z, bv1.w};
#pragma unroll
  for (int i = 0; i < 8; i++) {
    int row = by * 128 + ((i < 4) ? (ty * 4 + i) : (64 + ty * 4 + (i - 4)));
    float4 o0 = {acc[i][0] + bb8[0], acc[i][1] + bb8[1], acc[i][2] + bb8[2], acc[i][3] + bb8[3]};
    float4 o1 = {acc[i][4] + bb8[4], acc[i][5] + bb8[5], acc[i][6] + bb8[6], acc[i][7] + bb8[7]};
    *(float4*)(out + (size_t)row * 1024 + bx * 128 + tx * 4) = o0;
    *(float4*)(out + (size_t)row * 1024 + bx * 128 + 64 + tx * 4) = o1;
  }
}

// ---------------------------------------------------------------------------
// 3/5. Recurrence. grid: (NCAND=128 candidates, 2 dirs), block 256.
// a) Election: every WG publishes (ticket -> xcd) via agent atomics; all WGs
//    deterministically pick the first XCD with >=8 candidates (pigeonhole
//    over 128/8 guarantees one); first 8 tickets there own chunks 0..7.
// b) Probe: octet tests producer-store -> rd_l2 visibility with a BOUNDED
//    spin; votes exchanged over the proven agent path; use_l2 = all passed.
// c) Steady state (per step): FMA -> shfl reduce -> zbuf -> sync -> gates
//    (tid<32) -> publish (tag<<32|h_bits): pub_l2/rd_l2 if use_l2 else
//    relaxed agent atomics (R4) -> hbuf in LDS -> sync. Parity double-buffer.
// ---------------------------------------------------------------------------
__global__ __launch_bounds__(256) void recur_k(
    const float* __restrict__ xg_f, const float* __restrict__ xg_b,
    const float* __restrict__ Whh_f, const float* __restrict__ Whh_b,
    const float* __restrict__ bhh_f, const float* __restrict__ bhh_b,
    float* __restrict__ xnext, unsigned long long* __restrict__ hcomm_base,
    int* __restrict__ elect_base, unsigned long long* __restrict__ probe_base,
    int* __restrict__ vote_base) {
  int dir = blockIdx.y;         // 0=f, 1=b
  int tid = threadIdx.x;        // 0..255

  // ---- a) election -------------------------------------------------------
  int xcd;
  asm volatile("s_getreg_b32 %0, hwreg(HW_REG_XCC_ID)" : "=s"(xcd));
  xcd &= 7;
  int* cnt = elect_base + dir * (1 + NCAND);
  int* tab = cnt + 1;

  __shared__ int e_tab[NCAND];
  __shared__ int e_info[4];   // [0]=ticket, [1]=sel, [2]=kc, [3]=use_l2
  __shared__ int probe_ok[8];
  if (tid == 0) {
    int ticket = __hip_atomic_fetch_add(cnt, 1, __ATOMIC_RELAXED,
                                        __HIP_MEMORY_SCOPE_AGENT);
    __hip_atomic_store(&tab[ticket], xcd + 1, __ATOMIC_RELAXED,
                       __HIP_MEMORY_SCOPE_AGENT);
    e_info[0] = ticket;
  }
  if (tid < NCAND) {
    int v;
    do {
      v = __hip_atomic_load(&tab[tid], __ATOMIC_RELAXED,
                            __HIP_MEMORY_SCOPE_AGENT);
    } while (v == 0);
    e_tab[tid] = v - 1;
  }
  __syncthreads();
  if (tid == 0) {
    int ticket = e_info[0];
    int counts[8] = {0, 0, 0, 0, 0, 0, 0, 0};
    int home = -1;
    for (int i = 0; i < NCAND; i++) {
      int x = e_tab[i];
      counts[x]++;
      if (counts[x] == 8 && home < 0) home = x;
    }
    int sel = 0, kc = 0, probe = 0;
    if (home >= 0) {
      if (xcd == home) {
        int rank = 0;
        for (int i = 0; i < ticket; i++)
          if (e_tab[i] == home) rank++;
        if (rank < 8) { sel = 1; kc = rank; probe = 1; }
      }
    } else {
      if (ticket < 8) { sel = 1; kc = ticket; probe = 0; }
    }
    e_info[1] = sel; e_info[2] = kc; e_info[3] = probe;
  }
  __syncthreads();
  if (!e_info[1]) return;      // not selected: exit before loading weights
  int kc = e_info[2];
  int do_probe = e_info[3];
  int use_l2 = 0;

  // ---- b) coherence probe (bounded; decision via proven agent path) ------
  if (do_probe) {
    unsigned long long* probe = probe_base + (size_t)dir * 8 * 16;  // 128B/slot
    int* vote = vote_base + dir * 8;
    if (tid == 0) {
      pub_l2(&probe[kc * 16], 0xBEEF000000000000ull + (unsigned)kc);
    }
    if (tid < 8) {
      int found = 0;
      for (int iter = 0; iter < 3000 && !found; ++iter) {
        if (rd_l2(&probe[tid * 16]) ==
            0xBEEF000000000000ull + (unsigned)tid) found = 1;
      }
      probe_ok[tid] = found;
    }
    __syncthreads();
    if (tid == 0) {
      int ok = 1;
      for (int i = 0; i < 8; i++) ok &= probe_ok[i];
      // publish vote (1=fail, 2=pass) over the RELIABLE agent path
      __hip_atomic_store(&vote[kc], 1 + ok, __ATOMIC_RELAXED,
                         __HIP_MEMORY_SCOPE_AGENT);
    }
    if (tid < 8) {
      int v;
      do {
        v = __hip_atomic_load(&vote[tid], __ATOMIC_RELAXED,
                              __HIP_MEMORY_SCOPE_AGENT);
      } while (v == 0);   // bounded publishers => terminates
      probe_ok[tid] = v;
    }
    __syncthreads();
    if (tid == 0) {
      int all2 = 1;
      for (int i = 0; i < 8; i++) all2 &= (probe_ok[i] == 2);
      e_info[3] = all2;
    }
    __syncthreads();
    use_l2 = e_info[3];
  }

  // ---- c) setup ----------------------------------------------------------
  const float* Whh = dir ? Whh_b : Whh_f;
  const float* bhh = dir ? bhh_b : bhh_f;
  const float* xg = dir ? xg_b : xg_f;
  unsigned long long* hcomm = hcomm_base + (size_t)dir * 2 * HD;

  int r = tid >> 1;             // local row 0..127
  int half = tid & 1;           // which 128-col half
  int g = r >> 5;               // gate 0..3 (i,f,g,o)
  int kl = r & 31;
  int grow = g * 256 + kc * 32 + kl;  // global gate row 0..1023

  float4 Wv[32];
  const float4* wrow = (const float4*)(Whh + (size_t)grow * HD + half * 128);
#pragma unroll
  for (int j = 0; j < 32; j++) Wv[j] = wrow[j];
  float bias = bhh[grow];

  __shared__ __align__(16) float hbuf[HD];   // h_{t-1}
  __shared__ float zbuf[128];
  hbuf[tid] = 0.0f;
  __syncthreads();

  float c = 0.0f;               // cell state, used by tid<32
  bool is_remote = ((tid >> 5) != kc);  // this thread polls entry `tid`

#pragma unroll 1
  for (int it = 0; it < T_LEN; ++it) {
    int t = dir ? (T_LEN - 1 - it) : it;
    int p = it & 1;
    unsigned int tag = (unsigned)(it + 1);

    // prefetch xg early (even lanes only; consumed after the FMA loop)
    float xgv = 0.0f;
    if (!half) xgv = xg[(size_t)t * 1024 + grow];

    const float4* h4 = (const float4*)hbuf + half * 32;
    float4 acc = {0.f, 0.f, 0.f, 0.f};
#pragma unroll
    for (int j = 0; j < 32; j++) {
      float4 hv = h4[j];
      acc.x += Wv[j].x * hv.x;
      acc.y += Wv[j].y * hv.y;
      acc.z += Wv[j].z * hv.z;
      acc.w += Wv[j].w * hv.w;
    }
    float s = (acc.x + acc.y) + (acc.z + acc.w);
    s += __shfl_xor(s, 1, 64);   // combine the two halves of the row
    if (!half) zbuf[r] = s + xgv + bias;
    __syncthreads();             // zbuf ready; hbuf reads of h_{t-1} done

    if (tid < 32) {
      float zi = zbuf[tid];
      float zf = zbuf[32 + tid];
      float zg = zbuf[64 + tid];
      float zo = zbuf[96 + tid];
      c = fsig(zf) * c + fsig(zi) * ftanh(zg);
      float h = fsig(zo) * ftanh(c);
      union { float f; unsigned u; } cv;
      cv.f = h;
      unsigned long long pkt = ((unsigned long long)tag << 32) | cv.u;
      // publish FIRST (critical path), then feed next pipeline stage
      if (use_l2) {
        pub_l2(&hcomm[p * HD + kc * 32 + tid], pkt);
      } else {
        __hip_atomic_store(&hcomm[p * HD + kc * 32 + tid], pkt,
                           __ATOMIC_RELAXED, __HIP_MEMORY_SCOPE_AGENT);
      }
      xnext[(size_t)t * DMODEL + dir * HD + kc * 32 + tid] = h;
      hbuf[kc * 32 + tid] = h;
    }
    if (is_remote) {
      unsigned long long v;
      if (use_l2) {
        do { v = rd_l2(&hcomm[p * HD + tid]); } while ((unsigned)(v >> 32) != tag);
      } else {
        do {
          v = __hip_atomic_load(&hcomm[p * HD + tid], __ATOMIC_RELAXED,
                                __HIP_MEMORY_SCOPE_AGENT);
        } while ((unsigned)(v >> 32) != tag);
      }
      union { unsigned u; float f; } cv;
      cv.u = (unsigned)v;
      hbuf[tid] = cv.f;
    }
    __syncthreads();             // full h_t assembled in LDS
  }
}

// ---------------------------------------------------------------------------
// 6. Projection: feats[t][n] = x2[t][:] . W_out[n][:] + b_out[n]
// ---------------------------------------------------------------------------
__global__ void proj_k(const float* __restrict__ x2,
                       const float* __restrict__ Wo,
                       const float* __restrict__ bo,
                       float* __restrict__ feats) {
  int t = blockIdx.x;
  int tid = threadIdx.x;
  int n = tid & 31;
  int seg = tid >> 5;   // 0..7
  __shared__ float red[8][32];
  float s = 0.0f;
  if (n < NTAGS) {
    const float* xr = x2 + (size_t)t * DMODEL + seg * 64;
    const float* wr = Wo + (size_t)n * DMODEL + seg * 64;
#pragma unroll
    for (int j = 0; j < 64; j++) s += xr[j] * wr[j];
  }
  red[seg][n] = s;
  __syncthreads();
  if (tid < NTAGS) {
    float tot = bo[tid];
#pragma unroll
    for (int k = 0; k < 8; k++) tot += red[k][tid];
    feats[(size_t)t * NTAGS + tid] = tot;
  }
}

// ---------------------------------------------------------------------------
// 7. Viterbi: single block, 64 threads (one wave).
// ---------------------------------------------------------------------------
__global__ void viterbi_k(const float* __restrict__ feats,
                          const float* __restrict__ tr,
                          float* __restrict__ out) {
  __shared__ float v[NTAGS];
  __shared__ unsigned char bp[T_LEN * NTAGS];  // 40KB
  __shared__ float term[NTAGS];
  int tid = threadIdx.x;

  float trrow[NTAGS];
  if (tid < NTAGS) {
#pragma unroll
    for (int p = 0; p < NTAGS; p++) trrow[p] = tr[tid * NTAGS + p];
    v[tid] = (tid == START_TAG) ? 0.0f : -10000.0f;
  }
  __syncthreads();

#pragma unroll 1
  for (int t = 0; t < T_LEN; t++) {
    float fv = 0.0f;
    if (tid < NTAGS) fv = feats[(size_t)t * NTAGS + tid];
    float best = -3.4e38f;
    int arg = 0;
    if (tid < NTAGS) {
#pragma unroll
      for (int p = 0; p < NTAGS; p++) {
        float sc = v[p] + trrow[p];
        if (sc > best) { best = sc; arg = p; }
      }
      bp[t * NTAGS + tid] = (unsigned char)arg;
    }
    __syncthreads();
    if (tid < NTAGS) v[tid] = best + fv;
    __syncthreads();
  }

  if (tid < NTAGS) term[tid] = v[tid] + tr[END_TAG * NTAGS + tid];
  __syncthreads();
  if (tid == 0) {
    float bs = term[0];
    int bi = 0;
    for (int p = 1; p < NTAGS; p++) {
      if (term[p] > bs) { bs = term[p]; bi = p; }
    }
    out[0] = bs;
    int tag = bi;
    for (int t = T_LEN - 1; t >= 0; t--) {
      out[1 + t] = (float)tag;
      tag = bp[t * NTAGS + tag];
    }
  }
}

// ---------------------------------------------------------------------------
// Launch
// ---------------------------------------------------------------------------
extern "C" void kernel_launch(void* const* d_in, const int* in_sizes, int n_in,
                              void* d_out, int out_size, void* d_ws, size_t ws_size,
                              hipStream_t stream) {
  const int* sent = (const int*)d_in[0];
  const float* emb = (const float*)d_in[1];
  const float* l0f_Wih = (const float*)d_in[2];
  const float* l0f_Whh = (const float*)d_in[3];
  const float* l0f_bih = (const float*)d_in[4];
  const float* l0f_bhh = (const float*)d_in[5];
  const float* l0b_Wih = (const float*)d_in[6];
  const float* l0b_Whh = (const float*)d_in[7];
  const float* l0b_bih = (const float*)d_in[8];
  const float* l0b_bhh = (const float*)d_in[9];
  const float* l1f_Wih = (const float*)d_in[10];
  const float* l1f_Whh = (const float*)d_in[11];
  const float* l1f_bih = (const float*)d_in[12];
  const float* l1f_bhh = (const float*)d_in[13];
  const float* l1b_Wih = (const float*)d_in[14];
  const float* l1b_Whh = (const float*)d_in[15];
  const float* l1b_bih = (const float*)d_in[16];
  const float* l1b_bhh = (const float*)d_in[17];
  const float* W_out = (const float*)d_in[18];
  const float* b_out = (const float*)d_in[19];
  const float* transitions = (const float*)d_in[20];

  char* ws = (char*)d_ws;
  size_t off = 0;
  float* x0 = (float*)(ws + off);  off += (size_t)T_LEN * DMODEL * 4;          // 4MB
  float* xgf = (float*)(ws + off); off += (size_t)T_LEN * 1024 * 4;            // 8MB
  float* xgb = (float*)(ws + off); off += (size_t)T_LEN * 1024 * 4;            // 8MB
  float* x1 = (float*)(ws + off);  off += (size_t)T_LEN * DMODEL * 4;          // 4MB
  float* x2 = (float*)(ws + off);  off += (size_t)T_LEN * DMODEL * 4;          // 4MB
  float* feats = (float*)(ws + off); off += (size_t)T_LEN * NTAGS * 4;

  // sync area (single contiguous memset)
  off = (off + 127) & ~(size_t)127;
  char* sync_area = ws + off;
  unsigned long long* hcomm0 = (unsigned long long*)(sync_area);          // 8KB
  unsigned long long* hcomm1 = (unsigned long long*)(sync_area + 8192);   // 8KB
  int* elect0 = (int*)(sync_area + 16384);                                // 2KB
  int* elect1 = (int*)(sync_area + 18432);                                // 2KB
  unsigned long long* probe0 = (unsigned long long*)(sync_area + 20480);  // 2KB
  unsigned long long* probe1 = (unsigned long long*)(sync_area + 22528);  // 2KB
  int* vote0 = (int*)(sync_area + 24576);                                 // 1KB
  int* vote1 = (int*)(sync_area + 25600);                                 // 1KB
  size_t sync_bytes = 26624;
  off += sync_bytes;

  float* outf = (float*)d_out;

  // zero all sync state (d_ws is re-poisoned to 0xAA before every launch)
  (void)hipMemsetAsync(sync_area, 0, sync_bytes, stream);

  embed_k<<<dim3(T_LEN), dim3(128), 0, stream>>>(sent, emb, x0);

  gemm_xg_k<<<dim3(8, 16, 2), dim3(256), 0, stream>>>(
      x0, l0f_Wih, l0b_Wih, l0f_bih, l0b_bih, xgf, xgb);

  recur_k<<<dim3(NCAND, 2), dim3(256), 0, stream>>>(
      xgf, xgb, l0f_Whh, l0b_Whh, l0f_bhh, l0b_bhh, x1, hcomm0, elect0,
      probe0, vote0);

  gemm_xg_k<<<dim3(8, 16, 2), dim3(256), 0, stream>>>(
      x1, l1f_Wih, l1b_Wih, l1f_bih, l1b_bih, xgf, xgb);

  recur_k<<<dim3(NCAND, 2), dim3(256), 0, stream>>>(
      xgf, xgb, l1f_Whh, l1b_Whh, l1f_bhh, l1b_bhh, x2, hcomm1, elect1,
      probe1, vote1);

  proj_k<<<dim3(T_LEN), dim3(256), 0, stream>>>(x2, W_out, b_out, feats);

  viterbi_k<<<dim3(1), dim3(64), 0, stream>>>(feats, transitions, outf);
}